// Round 2
// baseline (612.269 us; speedup 1.0000x reference)
//
#include <hip/hip_runtime.h>
#include <hip/hip_cooperative_groups.h>
#include <math.h>

namespace cg = cooperative_groups;

#define HN 1024
#define VN 50257
#define SN 8192

// ws layout (float offsets) — identical footprint to the passing round
#define WS_PARTIAL 0          // 256*1024: per-rowchunk column partial sums
#define WS_AA      262144     // 1024: attn_applied (column mean)
#define WS_X       263168     // 1024: relu(combined)
#define WS_G       264192     // 6144: gi (3072) then gh (3072)
#define WS_LOGITS  271360     // 50257
#define WS_EXPD    321618     // 1024 doubles (8B-aligned: 321618*4 % 8 == 0)

__device__ __forceinline__ float wred(float v) {
#pragma unroll
  for (int m = 32; m; m >>= 1) v += __shfl_xor(v, m);
  return v;
}

__device__ __forceinline__ float dot4(float4 a, float4 b) {
  return a.x * b.x + a.y * b.y + a.z * b.z + a.w * b.w;
}

__global__ __launch_bounds__(256, 4) void mega(
    const int* __restrict__ token, const float* __restrict__ hidden,
    const float* __restrict__ enc, const float* __restrict__ embedding,
    const float* __restrict__ comb_w, const float* __restrict__ comb_b,
    const float* __restrict__ w_ih, const float* __restrict__ w_hh,
    const float* __restrict__ b_ih, const float* __restrict__ b_hh,
    const float* __restrict__ out_w, const float* __restrict__ out_b,
    float* __restrict__ out, float* __restrict__ ws) {
  cg::grid_group grid = cg::this_grid();
  const int blk = blockIdx.x;
  const int t = threadIdx.x;
  const int w = t >> 6, l = t & 63;

  __shared__ float4 hs4[256];   // h_new as 1024 floats (phase 5)
  __shared__ double sd[256];    // double reductions (phases 5,6)
  __shared__ float ssum[4];     // cross-wave partial (phase 3)

  // ---------------- P1: enc column-partials (blk<256) || gh = w_hh@h0
  // (256<=blk<512) || attn_weights out (blk==512) ----------------
  if (blk < 256) {
    const float4* e4 = (const float4*)enc + (size_t)blk * 32 * 256;
    float4 acc = make_float4(0.f, 0.f, 0.f, 0.f);
#pragma unroll 8
    for (int r = 0; r < 32; ++r) {
      float4 v = e4[r * 256 + t];
      acc.x += v.x; acc.y += v.y; acc.z += v.z; acc.w += v.w;
    }
    ((float4*)(ws + WS_PARTIAL))[blk * 256 + t] = acc;
  } else if (blk < 512) {
    const int wgid = (blk - 256) * 4 + w;          // 0..1023
    const float4* h4 = (const float4*)hidden;
    float4 hv0 = h4[l], hv1 = h4[64 + l], hv2 = h4[128 + l], hv3 = h4[192 + l];
#pragma unroll
    for (int k = 0; k < 3; ++k) {
      const int r = wgid + k * 1024;               // 0..3071
      const float4* m4 = (const float4*)w_hh + (size_t)r * 256;
      float acc = dot4(m4[l], hv0) + dot4(m4[64 + l], hv1) +
                  dot4(m4[128 + l], hv2) + dot4(m4[192 + l], hv3);
      acc = wred(acc);
      if (l == 0) ws[WS_G + 3072 + r] = acc;
    }
  } else if (blk == 512) {
#pragma unroll
    for (int j = 0; j < 32; ++j) out[VN + HN + t + j * 256] = 1.f / 8192.f;
  }
  grid.sync();

  // ---------------- P2: reduce partials -> attn_applied (column mean) ----
  if (blk < 4) {
    const int c = blk * 256 + t;
    float s = 0.f;
#pragma unroll 8
    for (int p = 0; p < 256; ++p) s += ws[WS_PARTIAL + p * 1024 + c];
    ws[WS_AA + c] = s * (1.f / 8192.f);
  }
  grid.sync();

  // ---------------- P3: x = relu([emb;aa] @ comb_w.T + b), row = blk -----
  {
    const float4* cw4 = (const float4*)comb_w + (size_t)blk * 512;
    const int tok = token[0];
    const float4* emb4 = (const float4*)embedding + (size_t)tok * 256;
    const float4* aa4 = (const float4*)(ws + WS_AA);
    float acc = 0.f;
#pragma unroll
    for (int j = 0; j < 2; ++j) {
      const int k4 = w * 128 + j * 64 + l;         // 0..511
      float4 wv = cw4[k4];
      float4 xv = (k4 < 256) ? emb4[k4] : aa4[k4 - 256];
      acc += dot4(wv, xv);
    }
    acc = wred(acc);
    if (l == 0) ssum[w] = acc;
    __syncthreads();
    if (t == 0) {
      float c = ssum[0] + ssum[1] + ssum[2] + ssum[3] + comb_b[blk];
      ws[WS_X + blk] = fmaxf(c, 0.f);
    }
  }
  grid.sync();

  // ---------------- P4: gi = w_ih @ x, wave per row ----------------------
  {
    const int gw = blk * 4 + w;                    // 0..4095
    if (gw < 3072) {
      const float4* m4 = (const float4*)w_ih + (size_t)gw * 256;
      const float4* x4 = (const float4*)(ws + WS_X);
      float acc = 0.f;
#pragma unroll
      for (int k = 0; k < 4; ++k) acc += dot4(m4[k * 64 + l], x4[k * 64 + l]);
      acc = wred(acc);
      if (l == 0) ws[WS_G + gw] = acc;
    }
  }
  grid.sync();

  // ---------------- P5: h_new (redundant per block, L2 reads) + logits ---
  {
    float* hsf = (float*)hs4;
    const float* g = ws + WS_G;
#pragma unroll
    for (int j = 0; j < 4; ++j) {
      const int i = t + j * 256;
      float ir = g[i] + b_ih[i];
      float iz = g[i + 1024] + b_ih[i + 1024];
      float inn = g[i + 2048] + b_ih[i + 2048];
      float hr = g[3072 + i] + b_hh[i];
      float hz = g[3072 + i + 1024] + b_hh[i + 1024];
      float hn = g[3072 + i + 2048] + b_hh[i + 2048];
      float rg = 1.f / (1.f + expf(-(ir + hr)));
      float zg = 1.f / (1.f + expf(-(iz + hz)));
      float ng = tanhf(inn + rg * hn);
      float h = (1.f - zg) * ng + zg * hidden[i];
      hsf[i] = h;
      if (blk == 0) out[VN + i] = h;               // h_new output
    }
    __syncthreads();

    float4 h0_ = hs4[l], h1_ = hs4[64 + l], h2_ = hs4[128 + l], h3_ = hs4[192 + l];
    const float4* ow4 = (const float4*)out_w;
    double eacc = 0.0;
    const int gw = blk * 4 + w;
    for (int v = gw; v < VN; v += 4096) {
      const float4* row = ow4 + (size_t)v * 256;
      float acc = dot4(row[l], h0_) + dot4(row[64 + l], h1_) +
                  dot4(row[128 + l], h2_) + dot4(row[192 + l], h3_);
      acc = wred(acc);
      if (l == 0) {
        float lg = acc + out_b[v];
        ws[WS_LOGITS + v] = lg;
        eacc += (double)expf(lg);   // |logit| small: no max-subtract needed
      }
    }
    __syncthreads();
    if (l == 0) sd[w] = eacc;
    __syncthreads();
    if (t == 0) ((double*)(ws + WS_EXPD))[blk] = sd[0] + sd[1] + sd[2] + sd[3];
  }
  grid.sync();

  // ---------------- P6: redundant deterministic logZ + final subtract ----
  {
    const double* ed = (const double*)(ws + WS_EXPD);
    double a = ed[t] + ed[t + 256] + ed[t + 512] + ed[t + 768];
    sd[t] = a;
    __syncthreads();
    for (int s = 128; s; s >>= 1) {
      if (t < s) sd[t] += sd[t + s];
      __syncthreads();
    }
    const float logZ = (float)log(sd[0]);
    const int v = blk * 256 + t;                   // covers 0..262143 >= VN
    if (v < VN) out[v] = ws[WS_LOGITS + v] - logZ;
  }
}

extern "C" void kernel_launch(void* const* d_in, const int* in_sizes, int n_in,
                              void* d_out, int out_size, void* d_ws, size_t ws_size,
                              hipStream_t stream) {
  const int* token = (const int*)d_in[0];
  const float* hidden = (const float*)d_in[1];
  const float* enc = (const float*)d_in[2];
  const float* embedding = (const float*)d_in[3];
  // d_in[4] attn_w, d_in[5] attn_b unused: softmax(broadcast(scalar)) is uniform
  const float* comb_w = (const float*)d_in[6];
  const float* comb_b = (const float*)d_in[7];
  const float* w_ih = (const float*)d_in[8];
  const float* w_hh = (const float*)d_in[9];
  const float* b_ih = (const float*)d_in[10];
  const float* b_hh = (const float*)d_in[11];
  const float* out_w = (const float*)d_in[12];
  const float* out_b = (const float*)d_in[13];
  float* out = (float*)d_out;
  float* ws = (float*)d_ws;

  void* args[] = {(void*)&token, (void*)&hidden, (void*)&enc, (void*)&embedding,
                  (void*)&comb_w, (void*)&comb_b, (void*)&w_ih, (void*)&w_hh,
                  (void*)&b_ih, (void*)&b_hh, (void*)&out_w, (void*)&out_b,
                  (void*)&out, (void*)&ws};
  hipLaunchCooperativeKernel(reinterpret_cast<void*>(mega), dim3(1024), dim3(256),
                             args, 0, stream);
}

// Round 3
// 72.224 us; speedup vs baseline: 8.4773x; 8.4773x over previous
//
#include <hip/hip_runtime.h>
#include <math.h>

#define HN 1024
#define VN 50257
#define SN 8192

// ws layout (float offsets)
#define WS_PARTIAL 0          // 256*1024: per-rowchunk column partial sums
#define WS_AA      262144     // 1024: attn_applied (column mean)
#define WS_X       263168     // 1024: relu(combined)
#define WS_G       264192     // 6144: gi (3072) then gh (3072)
#define WS_LOGITS  271360     // 50257
#define WS_EXPD    321618     // 1024 doubles (8B-aligned: 321618*4 % 8 == 0)

__device__ __forceinline__ float wred(float v) {
#pragma unroll
  for (int m = 32; m; m >>= 1) v += __shfl_xor(v, m);
  return v;
}

__device__ __forceinline__ float dot4(float4 a, float4 b) {
  return a.x * b.x + a.y * b.y + a.z * b.z + a.w * b.w;
}

// K1: block specialization — enc column partials (blk<256) || gh = w_hh@h0
// (256<=blk<512) || uniform attn_weights (blk==512). All independent.
__global__ void k1_front(const float* __restrict__ enc,
                         const float* __restrict__ w_hh,
                         const float* __restrict__ hidden,
                         float* __restrict__ ws, float* __restrict__ out_attn) {
  const int blk = blockIdx.x, t = threadIdx.x;
  if (blk < 256) {
    const float4* e4 = (const float4*)enc + (size_t)blk * 32 * 256;
    float4 acc = make_float4(0.f, 0.f, 0.f, 0.f);
#pragma unroll 8
    for (int r = 0; r < 32; ++r) {
      float4 v = e4[r * 256 + t];
      acc.x += v.x; acc.y += v.y; acc.z += v.z; acc.w += v.w;
    }
    ((float4*)(ws + WS_PARTIAL))[blk * 256 + t] = acc;
  } else if (blk < 512) {
    const int w = t >> 6, l = t & 63;
    const int wgid = (blk - 256) * 4 + w;          // 0..1023
    const float4* h4 = (const float4*)hidden;
    float4 hv0 = h4[l], hv1 = h4[64 + l], hv2 = h4[128 + l], hv3 = h4[192 + l];
#pragma unroll
    for (int k = 0; k < 3; ++k) {
      const int r = wgid + k * 1024;               // 0..3071
      const float4* m4 = (const float4*)w_hh + (size_t)r * 256;
      float acc = dot4(m4[l], hv0) + dot4(m4[64 + l], hv1) +
                  dot4(m4[128 + l], hv2) + dot4(m4[192 + l], hv3);
      acc = wred(acc);
      if (l == 0) ws[WS_G + 3072 + r] = acc;
    }
  } else {
#pragma unroll
    for (int j = 0; j < 32; ++j) out_attn[t + j * 256] = 1.f / 8192.f;
  }
}

// K2: reduce 256 rowchunk partials -> attn_applied (column mean)
__global__ void k2_reduce(float* __restrict__ ws) {
  const int c = blockIdx.x * 256 + threadIdx.x;  // 0..1023
  const float* p = ws + WS_PARTIAL;
  float s = 0.f;
#pragma unroll 8
  for (int rc = 0; rc < 256; ++rc) s += p[rc * 1024 + c];
  ws[WS_AA + c] = s * (1.f / 8192.f);
}

// K3: x = relu(concat(emb, attn_applied) @ comb_w.T + comb_b); wave per row
__global__ void k3_combined(const int* __restrict__ token,
                            const float* __restrict__ embedding,
                            const float* __restrict__ comb_w,
                            const float* __restrict__ comb_b,
                            float* __restrict__ ws) {
  const int w = threadIdx.x >> 6, l = threadIdx.x & 63;
  const int i = blockIdx.x * 4 + w;  // 0..1023
  const int tok = token[0];
  const float4* emb4 = (const float4*)embedding + (size_t)tok * 256;
  const float4* aa4 = (const float4*)(ws + WS_AA);
  const float4* cw4 = (const float4*)comb_w + (size_t)i * 512;
  float acc = 0.f;
#pragma unroll
  for (int k = 0; k < 8; ++k) {
    float4 wv = cw4[k * 64 + l];
    float4 xv = (k < 4) ? emb4[k * 64 + l] : aa4[(k - 4) * 64 + l];
    acc += dot4(wv, xv);
  }
  acc = wred(acc);
  if (l == 0) {
    float c = acc + comb_b[i];
    ws[WS_X + i] = fmaxf(c, 0.f);
  }
}

// K4: gi = w_ih @ x ; wave per row (rows 0..3071)
__global__ void k4_gates(const float* __restrict__ w_ih, float* __restrict__ ws) {
  const int w = threadIdx.x >> 6, l = threadIdx.x & 63;
  const int r = blockIdx.x * 4 + w;  // 0..3071
  const float4* m4 = (const float4*)w_ih + (size_t)r * 256;
  const float4* x4 = (const float4*)(ws + WS_X);
  float acc = 0.f;
#pragma unroll
  for (int k = 0; k < 4; ++k) acc += dot4(m4[k * 64 + l], x4[k * 64 + l]);
  acc = wred(acc);
  if (l == 0) ws[WS_G + r] = acc;
}

// K5: redundant per-block h_new from gate pre-activations (L2 reads), then
// logits GEMV + per-block exp partial sums. blk 0 writes h_new output.
__global__ void k5_logits(const float* __restrict__ b_ih, const float* __restrict__ b_hh,
                          const float* __restrict__ hidden,
                          const float* __restrict__ out_w, const float* __restrict__ out_b,
                          float* __restrict__ ws, float* __restrict__ d_out) {
  const int blk = blockIdx.x, t = threadIdx.x;
  const int w = t >> 6, l = t & 63;
  __shared__ float4 hs4[256];
  __shared__ double sd[4];
  float* hsf = (float*)hs4;
  const float* g = ws + WS_G;
#pragma unroll
  for (int j = 0; j < 4; ++j) {
    const int i = t + j * 256;
    float ir = g[i] + b_ih[i];
    float iz = g[i + 1024] + b_ih[i + 1024];
    float inn = g[i + 2048] + b_ih[i + 2048];
    float hr = g[3072 + i] + b_hh[i];
    float hz = g[3072 + i + 1024] + b_hh[i + 1024];
    float hn = g[3072 + i + 2048] + b_hh[i + 2048];
    float rg = 1.f / (1.f + expf(-(ir + hr)));
    float zg = 1.f / (1.f + expf(-(iz + hz)));
    float ng = tanhf(inn + rg * hn);
    float h = (1.f - zg) * ng + zg * hidden[i];
    hsf[i] = h;
    if (blk == 0) d_out[VN + i] = h;   // h_new output region
  }
  __syncthreads();

  float4 h0_ = hs4[l], h1_ = hs4[64 + l], h2_ = hs4[128 + l], h3_ = hs4[192 + l];
  const float4* ow4 = (const float4*)out_w;
  double eacc = 0.0;
  const int gw = blk * 4 + w;          // 0..4095
  for (int v = gw; v < VN; v += 4096) {
    const float4* row = ow4 + (size_t)v * 256;
    float acc = dot4(row[l], h0_) + dot4(row[64 + l], h1_) +
                dot4(row[128 + l], h2_) + dot4(row[192 + l], h3_);
    acc = wred(acc);
    if (l == 0) {
      float lg = acc + out_b[v];
      ws[WS_LOGITS + v] = lg;
      eacc += (double)expf(lg);        // |logit| small: no max-subtract needed
    }
  }
  if (l == 0) sd[w] = eacc;
  __syncthreads();
  if (t == 0) ((double*)(ws + WS_EXPD))[blk] = sd[0] + sd[1] + sd[2] + sd[3];
}

// K6: redundant deterministic logZ (fixed-order reduce of 1024 doubles) + subtract
__global__ void k6_final(const float* __restrict__ ws, float* __restrict__ d_out) {
  __shared__ double sd[256];
  const int t = threadIdx.x;
  const double* ed = (const double*)(ws + WS_EXPD);
  sd[t] = ed[t] + ed[t + 256] + ed[t + 512] + ed[t + 768];
  __syncthreads();
  for (int s = 128; s; s >>= 1) {
    if (t < s) sd[t] += sd[t + s];
    __syncthreads();
  }
  const float logZ = (float)log(sd[0]);
  const int v = blockIdx.x * 256 + t;
  if (v < VN) d_out[v] = ws[WS_LOGITS + v] - logZ;
}

extern "C" void kernel_launch(void* const* d_in, const int* in_sizes, int n_in,
                              void* d_out, int out_size, void* d_ws, size_t ws_size,
                              hipStream_t stream) {
  const int* token = (const int*)d_in[0];
  const float* hidden = (const float*)d_in[1];
  const float* enc = (const float*)d_in[2];
  const float* embedding = (const float*)d_in[3];
  // d_in[4] attn_w, d_in[5] attn_b unused: softmax(broadcast(scalar)) is uniform
  const float* comb_w = (const float*)d_in[6];
  const float* comb_b = (const float*)d_in[7];
  const float* w_ih = (const float*)d_in[8];
  const float* w_hh = (const float*)d_in[9];
  const float* b_ih = (const float*)d_in[10];
  const float* b_hh = (const float*)d_in[11];
  const float* out_w = (const float*)d_in[12];
  const float* out_b = (const float*)d_in[13];
  float* out = (float*)d_out;
  float* ws = (float*)d_ws;

  k1_front<<<513, 256, 0, stream>>>(enc, w_hh, hidden, ws, out + VN + HN);
  k2_reduce<<<4, 256, 0, stream>>>(ws);
  k3_combined<<<256, 256, 0, stream>>>(token, embedding, comb_w, comb_b, ws);
  k4_gates<<<768, 256, 0, stream>>>(w_ih, ws);
  k5_logits<<<1024, 256, 0, stream>>>(b_ih, b_hh, hidden, out_w, out_b, ws, out);
  k6_final<<<197, 256, 0, stream>>>(ws, out);
}

// Round 4
// 63.759 us; speedup vs baseline: 9.6028x; 1.1328x over previous
//
#include <hip/hip_runtime.h>
#include <math.h>

#define HN 1024
#define VN 50257
#define SN 8192

// ws layout (float offsets)
#define WS_PARTIAL 0          // 256*1024: per-rowchunk column partial sums
#define WS_AA      262144     // 1024: attn_applied (column mean)
#define WS_X       263168     // 1024: relu(combined)
#define WS_G       264192     // 6144: gi (3072) then gh (3072)
#define WS_HNEW    270336     // 1024: h_new
#define WS_LOGITS  271360     // 50257
#define WS_EXPD    321618     // 2048 doubles (8B-aligned: 321618*4 % 8 == 0)

__device__ __forceinline__ float wred(float v) {
#pragma unroll
  for (int m = 32; m; m >>= 1) v += __shfl_xor(v, m);
  return v;
}

__device__ __forceinline__ float dot4(float4 a, float4 b) {
  return a.x * b.x + a.y * b.y + a.z * b.z + a.w * b.w;
}

// K1 (320 blocks x 1024 thr): blk<256 -> enc column partials (32 rows/block,
// 4 row-groups x 256 cols, LDS reduce; 16 waves/block for latency hiding)
// + uniform attn_weights out. blk>=256 -> gh = w_hh @ h0 (1024 waves x 3 rows).
__global__ __launch_bounds__(1024) void k1_front(
    const float* __restrict__ enc, const float* __restrict__ w_hh,
    const float* __restrict__ hidden, float* __restrict__ ws,
    float* __restrict__ out_attn) {
  const int blk = blockIdx.x, t = threadIdx.x;
  if (blk < 256) {
    __shared__ float4 lds[1024];
    const int g = t >> 8, c4 = t & 255;
    const float4* e4 = (const float4*)enc + ((size_t)blk * 32 + g * 8) * 256 + c4;
    float4 acc = make_float4(0.f, 0.f, 0.f, 0.f);
#pragma unroll
    for (int r = 0; r < 8; ++r) {
      float4 v = e4[r * 256];
      acc.x += v.x; acc.y += v.y; acc.z += v.z; acc.w += v.w;
    }
    lds[t] = acc;
    __syncthreads();
    if (t < 256) {
      float4 a = lds[t], b = lds[t + 256], c = lds[t + 512], d = lds[t + 768];
      float4 s = make_float4(a.x + b.x + c.x + d.x, a.y + b.y + c.y + d.y,
                             a.z + b.z + c.z + d.z, a.w + b.w + c.w + d.w);
      ((float4*)(ws + WS_PARTIAL))[blk * 256 + t] = s;
    }
    if (t < 32) out_attn[blk * 32 + t] = 1.f / 8192.f;  // softmax(const) exact
  } else {
    const int wg = (blk - 256) * 16 + (t >> 6);  // 0..1023
    const int l = t & 63;
    const float4* h4 = (const float4*)hidden;
    float4 hv0 = h4[l], hv1 = h4[64 + l], hv2 = h4[128 + l], hv3 = h4[192 + l];
#pragma unroll
    for (int k = 0; k < 3; ++k) {
      const int r = wg + k * 1024;  // 0..3071
      const float4* m4 = (const float4*)w_hh + (size_t)r * 256;
      float acc = dot4(m4[l], hv0) + dot4(m4[64 + l], hv1) +
                  dot4(m4[128 + l], hv2) + dot4(m4[192 + l], hv3);
      acc = wred(acc);
      if (l == 0) ws[WS_G + 3072 + r] = acc;
    }
  }
}

// K2 (32 blocks x 256): reduce 256 rowchunk partials -> attn_applied.
// Block b: cols b*32..+32; 8 row-groups of 32; LDS cross-group reduce.
__global__ void k2_reduce(float* __restrict__ ws) {
  __shared__ float lds[256];
  const int t = threadIdx.x, b = blockIdx.x;
  const int c = b * 32 + (t & 31), rg = t >> 5;
  const float* p = ws + WS_PARTIAL;
  float s = 0.f;
#pragma unroll 8
  for (int j = 0; j < 32; ++j) s += p[(rg * 32 + j) * 1024 + c];
  lds[t] = s;
  __syncthreads();
  if (t < 32) {
    float a = 0.f;
#pragma unroll
    for (int j = 0; j < 8; ++j) a += lds[j * 32 + t];
    ws[WS_AA + b * 32 + t] = a * (1.f / 8192.f);
  }
}

// K3: x = relu(concat(emb, attn_applied) @ comb_w.T + comb_b); wave per row
__global__ void k3_combined(const int* __restrict__ token,
                            const float* __restrict__ embedding,
                            const float* __restrict__ comb_w,
                            const float* __restrict__ comb_b,
                            float* __restrict__ ws) {
  const int w = threadIdx.x >> 6, l = threadIdx.x & 63;
  const int i = blockIdx.x * 4 + w;  // 0..1023
  const int tok = token[0];
  const float4* emb4 = (const float4*)embedding + (size_t)tok * 256;
  const float4* aa4 = (const float4*)(ws + WS_AA);
  const float4* cw4 = (const float4*)comb_w + (size_t)i * 512;
  float acc = 0.f;
#pragma unroll
  for (int k = 0; k < 8; ++k) {
    float4 wv = cw4[k * 64 + l];
    float4 xv = (k < 4) ? emb4[k * 64 + l] : aa4[(k - 4) * 64 + l];
    acc += dot4(wv, xv);
  }
  acc = wred(acc);
  if (l == 0) {
    float c = acc + comb_b[i];
    ws[WS_X + i] = fmaxf(c, 0.f);
  }
}

// K4: gi = w_ih @ x ; wave per row (rows 0..3071)
__global__ void k4_gates(const float* __restrict__ w_ih, float* __restrict__ ws) {
  const int w = threadIdx.x >> 6, l = threadIdx.x & 63;
  const int r = blockIdx.x * 4 + w;  // 0..3071
  const float4* m4 = (const float4*)w_ih + (size_t)r * 256;
  const float4* x4 = (const float4*)(ws + WS_X);
  float acc = 0.f;
#pragma unroll
  for (int k = 0; k < 4; ++k) acc += dot4(m4[k * 64 + l], x4[k * 64 + l]);
  acc = wred(acc);
  if (l == 0) ws[WS_G + r] = acc;
}

// K4b (1 block): GRU gate math -> h_new (ws + d_out)
__global__ void k4b_hnew(const float* __restrict__ b_ih, const float* __restrict__ b_hh,
                         const float* __restrict__ hidden, float* __restrict__ ws,
                         float* __restrict__ d_out) {
  const int t = threadIdx.x;
  const float* g = ws + WS_G;
#pragma unroll
  for (int j = 0; j < 4; ++j) {
    const int i = t + j * 256;
    float ir = g[i] + b_ih[i];
    float iz = g[i + 1024] + b_ih[i + 1024];
    float inn = g[i + 2048] + b_ih[i + 2048];
    float hr = g[3072 + i] + b_hh[i];
    float hz = g[3072 + i + 1024] + b_hh[i + 1024];
    float hn = g[3072 + i + 2048] + b_hh[i + 2048];
    float rg = 1.f / (1.f + expf(-(ir + hr)));
    float zg = 1.f / (1.f + expf(-(iz + hz)));
    float ng = tanhf(inn + rg * hn);
    float h = (1.f - zg) * ng + zg * hidden[i];
    ws[WS_HNEW + i] = h;
    d_out[VN + i] = h;  // h_new output region
  }
}

// K5 (2048 blocks x 256): logits GEMV, 2 rows in flight per wave, per-block
// exp partial sums (fixed order -> deterministic).
__global__ void k5_logits(const float* __restrict__ out_w, const float* __restrict__ out_b,
                          float* __restrict__ ws) {
  const int blk = blockIdx.x, t = threadIdx.x;
  const int w = t >> 6, l = t & 63;
  const int gw = blk * 4 + w;  // 0..8191
  const float4* h4p = (const float4*)(ws + WS_HNEW);
  float4 h0_ = h4p[l], h1_ = h4p[64 + l], h2_ = h4p[128 + l], h3_ = h4p[192 + l];
  const float4* ow4 = (const float4*)out_w;
  double eacc = 0.0;
  for (int v = gw; v < VN; v += 16384) {
    const int v2 = v + 8192;
    const bool ok2 = (v2 < VN);                    // wave-uniform
    const float4* r0 = ow4 + (size_t)v * 256;
    const float4* r1 = ow4 + (size_t)(ok2 ? v2 : v) * 256;  // clamp: stays in-bounds
    float acc0 = dot4(r0[l], h0_) + dot4(r0[64 + l], h1_) +
                 dot4(r0[128 + l], h2_) + dot4(r0[192 + l], h3_);
    float acc1 = dot4(r1[l], h0_) + dot4(r1[64 + l], h1_) +
                 dot4(r1[128 + l], h2_) + dot4(r1[192 + l], h3_);
    acc0 = wred(acc0);
    acc1 = wred(acc1);
    if (l == 0) {
      float lg0 = acc0 + out_b[v];
      ws[WS_LOGITS + v] = lg0;
      eacc += (double)expf(lg0);  // |logit| small: no max-subtract needed
      if (ok2) {
        float lg1 = acc1 + out_b[v2];
        ws[WS_LOGITS + v2] = lg1;
        eacc += (double)expf(lg1);
      }
    }
  }
  __shared__ double sd[4];
  if (l == 0) sd[w] = eacc;
  __syncthreads();
  if (t == 0) ((double*)(ws + WS_EXPD))[blk] = sd[0] + sd[1] + sd[2] + sd[3];
}

// K6: redundant deterministic logZ (fixed-order reduce of 2048 doubles) + subtract
__global__ void k6_final(const float* __restrict__ ws, float* __restrict__ d_out) {
  __shared__ double sd[256];
  const int t = threadIdx.x;
  const double* ed = (const double*)(ws + WS_EXPD);
  double a = 0.0;
#pragma unroll
  for (int j = 0; j < 8; ++j) a += ed[t + j * 256];
  sd[t] = a;
  __syncthreads();
  for (int s = 128; s; s >>= 1) {
    if (t < s) sd[t] += sd[t + s];
    __syncthreads();
  }
  const float logZ = (float)log(sd[0]);
  const int v = blockIdx.x * 256 + t;
  if (v < VN) d_out[v] = ws[WS_LOGITS + v] - logZ;
}

extern "C" void kernel_launch(void* const* d_in, const int* in_sizes, int n_in,
                              void* d_out, int out_size, void* d_ws, size_t ws_size,
                              hipStream_t stream) {
  const int* token = (const int*)d_in[0];
  const float* hidden = (const float*)d_in[1];
  const float* enc = (const float*)d_in[2];
  const float* embedding = (const float*)d_in[3];
  // d_in[4] attn_w, d_in[5] attn_b unused: softmax(broadcast(scalar)) is uniform
  const float* comb_w = (const float*)d_in[6];
  const float* comb_b = (const float*)d_in[7];
  const float* w_ih = (const float*)d_in[8];
  const float* w_hh = (const float*)d_in[9];
  const float* b_ih = (const float*)d_in[10];
  const float* b_hh = (const float*)d_in[11];
  const float* out_w = (const float*)d_in[12];
  const float* out_b = (const float*)d_in[13];
  float* out = (float*)d_out;
  float* ws = (float*)d_ws;

  k1_front<<<320, 1024, 0, stream>>>(enc, w_hh, hidden, ws, out + VN + HN);
  k2_reduce<<<32, 256, 0, stream>>>(ws);
  k3_combined<<<256, 256, 0, stream>>>(token, embedding, comb_w, comb_b, ws);
  k4_gates<<<768, 256, 0, stream>>>(w_ih, ws);
  k4b_hnew<<<1, 256, 0, stream>>>(b_ih, b_hh, hidden, ws, out);
  k5_logits<<<2048, 256, 0, stream>>>(out_w, out_b, ws);
  k6_final<<<197, 256, 0, stream>>>(ws, out);
}

// Round 5
// 60.866 us; speedup vs baseline: 10.0593x; 1.0475x over previous
//
#include <hip/hip_runtime.h>
#include <math.h>

#define HN 1024
#define VN 50257
#define SN 8192

// ws layout (float offsets)
#define WS_PARTIAL 0          // 256*1024: per-rowchunk column partial sums
#define WS_AA      262144     // 1024: attn_applied (column mean)
#define WS_X       263168     // 1024: relu(combined)
#define WS_GH      264192     // 3072: raw w_hh @ h0
#define WS_CEMB    267264     // 1024: comb_w[:, :H] @ emb + comb_b
#define WS_HNEW    270336     // 1024: h_new
#define WS_LOGITS  271360     // 50257
#define WS_EXPD    321618     // 2048 doubles (8B-aligned: 321618*4 % 8 == 0)

__device__ __forceinline__ float wred(float v) {
#pragma unroll
  for (int m = 32; m; m >>= 1) v += __shfl_xor(v, m);
  return v;
}

__device__ __forceinline__ float dot4(float4 a, float4 b) {
  return a.x * b.x + a.y * b.y + a.z * b.z + a.w * b.w;
}

// K1 (384 blocks x 1024 thr), block-specialized independent work:
//   blk<256  : enc column partials (32 rows/blk, LDS reduce) + attn_weights out
//   256..319 : gh = w_hh @ h0 (raw, no bias)
//   320..383 : c_emb = comb_w[:, :H] @ emb + comb_b   (emb half needs no aa)
__global__ __launch_bounds__(1024) void k1_front(
    const float* __restrict__ enc, const float* __restrict__ w_hh,
    const float* __restrict__ hidden, const int* __restrict__ token,
    const float* __restrict__ embedding, const float* __restrict__ comb_w,
    const float* __restrict__ comb_b, float* __restrict__ ws,
    float* __restrict__ out_attn) {
  const int blk = blockIdx.x, t = threadIdx.x;
  if (blk < 256) {
    __shared__ float4 lds[1024];
    const int g = t >> 8, c4 = t & 255;
    const float4* e4 = (const float4*)enc + ((size_t)blk * 32 + g * 8) * 256 + c4;
    float4 acc = make_float4(0.f, 0.f, 0.f, 0.f);
#pragma unroll
    for (int r = 0; r < 8; ++r) {
      float4 v = e4[r * 256];
      acc.x += v.x; acc.y += v.y; acc.z += v.z; acc.w += v.w;
    }
    lds[t] = acc;
    __syncthreads();
    if (t < 256) {
      float4 a = lds[t], b = lds[t + 256], c = lds[t + 512], d = lds[t + 768];
      float4 s = make_float4(a.x + b.x + c.x + d.x, a.y + b.y + c.y + d.y,
                             a.z + b.z + c.z + d.z, a.w + b.w + c.w + d.w);
      ((float4*)(ws + WS_PARTIAL))[blk * 256 + t] = s;
    }
    if (t < 32) out_attn[blk * 32 + t] = 1.f / 8192.f;  // softmax(const) exact
  } else if (blk < 320) {
    const int wg = (blk - 256) * 16 + (t >> 6);  // 0..1023
    const int l = t & 63;
    const float4* h4 = (const float4*)hidden;
    float4 hv0 = h4[l], hv1 = h4[64 + l], hv2 = h4[128 + l], hv3 = h4[192 + l];
#pragma unroll
    for (int k = 0; k < 3; ++k) {
      const int r = wg + k * 1024;  // 0..3071
      const float4* m4 = (const float4*)w_hh + (size_t)r * 256;
      float acc = dot4(m4[l], hv0) + dot4(m4[64 + l], hv1) +
                  dot4(m4[128 + l], hv2) + dot4(m4[192 + l], hv3);
      acc = wred(acc);
      if (l == 0) ws[WS_GH + r] = acc;
    }
  } else {
    const int i = (blk - 320) * 16 + (t >> 6);  // 0..1023
    const int l = t & 63;
    const int tok = token[0];
    const float4* emb4 = (const float4*)embedding + (size_t)tok * 256;
    const float4* cw4 = (const float4*)comb_w + (size_t)i * 512;  // first half
    float acc = 0.f;
#pragma unroll
    for (int k = 0; k < 4; ++k) acc += dot4(cw4[k * 64 + l], emb4[k * 64 + l]);
    acc = wred(acc);
    if (l == 0) ws[WS_CEMB + i] = acc + comb_b[i];
  }
}

// K2 (32 blocks x 256): reduce 256 rowchunk partials -> attn_applied.
__global__ void k2_reduce(float* __restrict__ ws) {
  __shared__ float lds[256];
  const int t = threadIdx.x, b = blockIdx.x;
  const int c = b * 32 + (t & 31), rg = t >> 5;
  const float* p = ws + WS_PARTIAL;
  float s = 0.f;
#pragma unroll 8
  for (int j = 0; j < 32; ++j) s += p[(rg * 32 + j) * 1024 + c];
  lds[t] = s;
  __syncthreads();
  if (t < 32) {
    float a = 0.f;
#pragma unroll
    for (int j = 0; j < 8; ++j) a += lds[j * 32 + t];
    ws[WS_AA + b * 32 + t] = a * (1.f / 8192.f);
  }
}

// K3 (256 blocks x 256): x = relu(c_emb + comb_w[:, H:] @ aa); wave per row
__global__ void k3_x(const float* __restrict__ comb_w, float* __restrict__ ws) {
  const int w = threadIdx.x >> 6, l = threadIdx.x & 63;
  const int i = blockIdx.x * 4 + w;  // 0..1023
  const float4* aa4 = (const float4*)(ws + WS_AA);
  const float4* cw4 = (const float4*)comb_w + (size_t)i * 512 + 256;  // second half
  float acc = 0.f;
#pragma unroll
  for (int k = 0; k < 4; ++k) acc += dot4(cw4[k * 64 + l], aa4[k * 64 + l]);
  acc = wred(acc);
  if (l == 0) ws[WS_X + i] = fmaxf(ws[WS_CEMB + i] + acc, 0.f);
}

// K4 (256 blocks x 256): wave computes all 3 gi rows for its i, then lane 0
// applies GRU gate math -> h_new. No gi round-trip, no separate h kernel.
__global__ void k4_gates_h(const float* __restrict__ w_ih,
                           const float* __restrict__ b_ih, const float* __restrict__ b_hh,
                           const float* __restrict__ hidden, float* __restrict__ ws,
                           float* __restrict__ d_out) {
  const int w = threadIdx.x >> 6, l = threadIdx.x & 63;
  const int i = blockIdx.x * 4 + w;  // 0..1023
  const float4* x4 = (const float4*)(ws + WS_X);
  float4 xv0 = x4[l], xv1 = x4[64 + l], xv2 = x4[128 + l], xv3 = x4[192 + l];
  const float4* m0 = (const float4*)w_ih + (size_t)i * 256;
  const float4* m1 = (const float4*)w_ih + (size_t)(i + 1024) * 256;
  const float4* m2 = (const float4*)w_ih + (size_t)(i + 2048) * 256;
  float a0 = dot4(m0[l], xv0) + dot4(m0[64 + l], xv1) +
             dot4(m0[128 + l], xv2) + dot4(m0[192 + l], xv3);
  float a1 = dot4(m1[l], xv0) + dot4(m1[64 + l], xv1) +
             dot4(m1[128 + l], xv2) + dot4(m1[192 + l], xv3);
  float a2 = dot4(m2[l], xv0) + dot4(m2[64 + l], xv1) +
             dot4(m2[128 + l], xv2) + dot4(m2[192 + l], xv3);
  a0 = wred(a0); a1 = wred(a1); a2 = wred(a2);
  if (l == 0) {
    float ir = a0 + b_ih[i];
    float iz = a1 + b_ih[i + 1024];
    float inn = a2 + b_ih[i + 2048];
    float hr = ws[WS_GH + i] + b_hh[i];
    float hz = ws[WS_GH + i + 1024] + b_hh[i + 1024];
    float hn = ws[WS_GH + i + 2048] + b_hh[i + 2048];
    float rg = 1.f / (1.f + expf(-(ir + hr)));
    float zg = 1.f / (1.f + expf(-(iz + hz)));
    float ng = tanhf(inn + rg * hn);
    float h = (1.f - zg) * ng + zg * hidden[i];
    ws[WS_HNEW + i] = h;
    d_out[VN + i] = h;  // h_new output region
  }
}

// K5 (2048 blocks x 256): logits GEMV, 3-row ILP, exact coverage
// (2 full iters cover rows 0..49151; tail row for gw<1105 covers the rest).
__global__ void k5_logits(const float* __restrict__ out_w, const float* __restrict__ out_b,
                          float* __restrict__ ws) {
  const int blk = blockIdx.x, t = threadIdx.x;
  const int w = t >> 6, l = t & 63;
  const int gw = blk * 4 + w;  // 0..8191
  __shared__ float4 hs4[256];
  __shared__ double sd[4];
  if (t < 256) hs4[t] = ((const float4*)(ws + WS_HNEW))[t];
  __syncthreads();
  float4 h0_ = hs4[l], h1_ = hs4[64 + l], h2_ = hs4[128 + l], h3_ = hs4[192 + l];
  const float4* ow4 = (const float4*)out_w;
  double eacc = 0.0;
#pragma unroll
  for (int it = 0; it < 2; ++it) {
    const int v0 = gw + it * 24576;
    const float4* r0 = ow4 + (size_t)v0 * 256;
    const float4* r1 = r0 + 8192 * 256;
    const float4* r2 = r1 + 8192 * 256;
    float a0 = dot4(r0[l], h0_) + dot4(r0[64 + l], h1_) +
               dot4(r0[128 + l], h2_) + dot4(r0[192 + l], h3_);
    float a1 = dot4(r1[l], h0_) + dot4(r1[64 + l], h1_) +
               dot4(r1[128 + l], h2_) + dot4(r1[192 + l], h3_);
    float a2 = dot4(r2[l], h0_) + dot4(r2[64 + l], h1_) +
               dot4(r2[128 + l], h2_) + dot4(r2[192 + l], h3_);
    a0 = wred(a0); a1 = wred(a1); a2 = wred(a2);
    if (l == 0) {
      float lg0 = a0 + out_b[v0];
      float lg1 = a1 + out_b[v0 + 8192];
      float lg2 = a2 + out_b[v0 + 16384];
      ws[WS_LOGITS + v0] = lg0;
      ws[WS_LOGITS + v0 + 8192] = lg1;
      ws[WS_LOGITS + v0 + 16384] = lg2;
      eacc += (double)expf(lg0) + (double)expf(lg1) + (double)expf(lg2);
    }
  }
  if (gw < 1105) {  // tail rows 49152..50256
    const int v = gw + 49152;
    const float4* r0 = ow4 + (size_t)v * 256;
    float a = dot4(r0[l], h0_) + dot4(r0[64 + l], h1_) +
              dot4(r0[128 + l], h2_) + dot4(r0[192 + l], h3_);
    a = wred(a);
    if (l == 0) {
      float lg = a + out_b[v];
      ws[WS_LOGITS + v] = lg;
      eacc += (double)expf(lg);
    }
  }
  if (l == 0) sd[w] = eacc;
  __syncthreads();
  if (t == 0) ((double*)(ws + WS_EXPD))[blk] = sd[0] + sd[1] + sd[2] + sd[3];
}

// K6: redundant deterministic logZ (fixed-order reduce of 2048 doubles) + subtract
__global__ void k6_final(const float* __restrict__ ws, float* __restrict__ d_out) {
  __shared__ double sd[256];
  const int t = threadIdx.x;
  const double* ed = (const double*)(ws + WS_EXPD);
  double a = 0.0;
#pragma unroll
  for (int j = 0; j < 8; ++j) a += ed[t + j * 256];
  sd[t] = a;
  __syncthreads();
  for (int s = 128; s; s >>= 1) {
    if (t < s) sd[t] += sd[t + s];
    __syncthreads();
  }
  const float logZ = (float)log(sd[0]);
  const int v = blockIdx.x * 256 + t;
  if (v < VN) d_out[v] = ws[WS_LOGITS + v] - logZ;
}

extern "C" void kernel_launch(void* const* d_in, const int* in_sizes, int n_in,
                              void* d_out, int out_size, void* d_ws, size_t ws_size,
                              hipStream_t stream) {
  const int* token = (const int*)d_in[0];
  const float* hidden = (const float*)d_in[1];
  const float* enc = (const float*)d_in[2];
  const float* embedding = (const float*)d_in[3];
  // d_in[4] attn_w, d_in[5] attn_b unused: softmax(broadcast(scalar)) is uniform
  const float* comb_w = (const float*)d_in[6];
  const float* comb_b = (const float*)d_in[7];
  const float* w_ih = (const float*)d_in[8];
  const float* w_hh = (const float*)d_in[9];
  const float* b_ih = (const float*)d_in[10];
  const float* b_hh = (const float*)d_in[11];
  const float* out_w = (const float*)d_in[12];
  const float* out_b = (const float*)d_in[13];
  float* out = (float*)d_out;
  float* ws = (float*)d_ws;

  k1_front<<<384, 1024, 0, stream>>>(enc, w_hh, hidden, token, embedding,
                                     comb_w, comb_b, ws, out + VN + HN);
  k2_reduce<<<32, 256, 0, stream>>>(ws);
  k3_x<<<256, 256, 0, stream>>>(comb_w, ws);
  k4_gates_h<<<256, 256, 0, stream>>>(w_ih, b_ih, b_hh, hidden, ws, out);
  k5_logits<<<2048, 256, 0, stream>>>(out_w, out_b, ws);
  k6_final<<<197, 256, 0, stream>>>(ws, out);
}